// Round 2
// baseline (480.407 us; speedup 1.0000x reference)
//
#include <hip/hip_runtime.h>

typedef __bf16 bf16;
typedef __attribute__((ext_vector_type(4))) __bf16 bf16x4;
typedef __attribute__((ext_vector_type(8))) __bf16 bf16x8;
typedef __attribute__((ext_vector_type(4))) float f32x4;

#define MFMA_BF16(A_, B_, C_) __builtin_amdgcn_mfma_f32_16x16x32_bf16(A_, B_, C_, 0, 0, 0)

// Problem dims
#define BB    32
#define SEQ   577
#define CH    768
#define NH    12
#define DHD   64
#define MROWS (BB * SEQ)   // 18464
#define MPAD  18560        // 145 * 128 (zero-padded rows; GEMM staging needs no bounds checks)
#define NQKV  2304

// ---- async global->LDS 16B (wave-uniform LDS base + lane*16, per guide §5) ----
__device__ __forceinline__ void async_ld16(const bf16* g, bf16* l) {
  __builtin_amdgcn_global_load_lds(
      (const __attribute__((address_space(1))) void*)g,
      (__attribute__((address_space(3))) void*)l, 16, 0, 0);
}

// ---- fp32 -> bf16 convert, zero-fill tail [nsrc, ntot) ----
__global__ __launch_bounds__(256) void cvt_bf16(const float* __restrict__ src,
                                                bf16* __restrict__ dst,
                                                int nsrc, int ntot) {
  int idx = (blockIdx.x * 256 + threadIdx.x) * 4;
  if (idx >= ntot) return;
  if (idx < nsrc) {
    float4 v = *(const float4*)(src + idx);
    bf16x4 o = {(bf16)v.x, (bf16)v.y, (bf16)v.z, (bf16)v.w};
    *(bf16x4*)(dst + idx) = o;
  } else {
    bf16x4 z = {(bf16)0.f, (bf16)0.f, (bf16)0.f, (bf16)0.f};
    *(bf16x4*)(dst + idx) = z;
  }
}

// ---- 128x128x(K=768) bf16 MFMA GEMM, BK=32, B given as rows of W [n][k] (x @ W^T) ----
// EPI 0: qkv epilogue (bias, q*=0.125, scatter to q/k/v [B,H,N,DH] bf16)
// EPI 1: proj epilogue (bias, fp32 out [M, 768])
template <int EPI>
__global__ __launch_bounds__(256, 2)
void gemm_bt(const bf16* __restrict__ A, const bf16* __restrict__ W,
             const float* __restrict__ bias,
             bf16* __restrict__ qb, bf16* __restrict__ kb, bf16* __restrict__ vb,
             float* __restrict__ out) {
  __shared__ bf16 As[128 * 32];
  __shared__ bf16 Bs[128 * 32];
  const int tid = threadIdx.x, lane = tid & 63, wid = tid >> 6;
  const int quad = lane >> 4, r15 = lane & 15;
  const int m0 = blockIdx.x * 128, n0 = blockIdx.y * 128;
  const int waveM = wid & 1, waveN = wid >> 1;

  // staging: 512 16B chunks per tile; chunk q -> row=q>>2, LDS slot q holds global
  // k-chunk (q&3)^sw(row) (XOR swizzle so fragment ds_read_b128 is 2-way conflict = free)
  const bf16* aSrc[2];
  const bf16* bSrc[2];
  for (int c = 0; c < 2; ++c) {
    int q = wid * 128 + c * 64 + lane;
    int row = q >> 2;
    int sw = (row ^ (row >> 2)) & 3;
    int kc = (q & 3) ^ sw;
    aSrc[c] = A + (size_t)(m0 + row) * CH + kc * 8;
    bSrc[c] = W + (size_t)(n0 + row) * CH + kc * 8;
  }

  f32x4 acc[4][4];
#pragma unroll
  for (int i = 0; i < 4; ++i)
#pragma unroll
    for (int j = 0; j < 4; ++j) acc[i][j] = (f32x4){0.f, 0.f, 0.f, 0.f};

  for (int k0 = 0; k0 < CH; k0 += 32) {
    __syncthreads();  // protect previous iteration's LDS reads
#pragma unroll
    for (int c = 0; c < 2; ++c) {
      async_ld16(aSrc[c] + k0, As + (wid * 128 + c * 64) * 8);
      async_ld16(bSrc[c] + k0, Bs + (wid * 128 + c * 64) * 8);
    }
    __syncthreads();  // compiler emits vmcnt(0) drain before barrier

    bf16x8 af[4], bfr[4];
#pragma unroll
    for (int s = 0; s < 4; ++s) {
      int rowA = waveM * 64 + s * 16 + r15;
      int ca = quad ^ ((rowA ^ (rowA >> 2)) & 3);
      af[s] = *(const bf16x8*)(As + rowA * 32 + ca * 8);
      int rowB = waveN * 64 + s * 16 + r15;
      int cb = quad ^ ((rowB ^ (rowB >> 2)) & 3);
      bfr[s] = *(const bf16x8*)(Bs + rowB * 32 + cb * 8);
    }
#pragma unroll
    for (int sm = 0; sm < 4; ++sm)
#pragma unroll
      for (int sn = 0; sn < 4; ++sn)
        acc[sm][sn] = MFMA_BF16(af[sm], bfr[sn], acc[sm][sn]);
  }

  // epilogue: C/D layout row=(lane>>4)*4+reg, col=lane&15 (verified m89/m91)
  if (EPI == 0) {
    int t = n0 / CH;  // 128-tiles never straddle a 768 boundary -> block-uniform
    bf16* dst = (t == 0) ? qb : (t == 1) ? kb : vb;
    float mul = (t == 0) ? 0.125f : 1.0f;
#pragma unroll
    for (int sn = 0; sn < 4; ++sn) {
      int gn = n0 + waveN * 64 + sn * 16 + r15;
      float bv = bias[gn];
      int h = (gn >> 6) % NH;
      int d = gn & 63;
#pragma unroll
      for (int sm = 0; sm < 4; ++sm) {
        int gmBase = m0 + waveM * 64 + sm * 16 + quad * 4;
#pragma unroll
        for (int r = 0; r < 4; ++r) {
          int gm = gmBase + r;
          if (gm < MROWS) {
            int b_ = gm / SEQ;
            int n_ = gm - b_ * SEQ;
            float v = (acc[sm][sn][r] + bv) * mul;
            dst[(((size_t)(b_ * NH + h) * SEQ) + n_) * DHD + d] = (bf16)v;
          }
        }
      }
    }
  } else {
#pragma unroll
    for (int sn = 0; sn < 4; ++sn) {
      int gn = n0 + waveN * 64 + sn * 16 + r15;
      float bv = bias[gn];
#pragma unroll
      for (int sm = 0; sm < 4; ++sm) {
        int gmBase = m0 + waveM * 64 + sm * 16 + quad * 4;
#pragma unroll
        for (int r = 0; r < 4; ++r) {
          int gm = gmBase + r;
          if (gm < MROWS) out[(size_t)gm * CH + gn] = acc[sm][sn][r] + bv;
        }
      }
    }
  }
}

// ---- flash attention: block = (b*NH+h, 64-row q-tile), 4 waves x 16 rows ----
__global__ __launch_bounds__(256, 2)
void attn_kernel(const bf16* __restrict__ qb, const bf16* __restrict__ kb,
                 const bf16* __restrict__ vb, bf16* __restrict__ ob) {
  __shared__ bf16 Ks[64 * 72];      // K tile rows [j][d], padded 72
  __shared__ bf16 Vt[64 * 72];      // V^T tile [d][j], padded 72
  __shared__ bf16 Pb[4][16 * 72];   // per-wave P round-trip, padded 72
  const int tid = threadIdx.x, lane = tid & 63, wid = tid >> 6;
  const int quad = lane >> 4, r15 = lane & 15;
  const int qt = blockIdx.x, bh = blockIdx.y;
  const size_t base = (size_t)bh * SEQ * DHD;

  // Q fragments resident in registers (A layout: m=lane&15, k=quad*8+j)
  int qrow = qt * 64 + wid * 16 + r15;
  if (qrow > SEQ - 1) qrow = SEQ - 1;
  const bf16* qp = qb + base + (size_t)qrow * DHD + quad * 8;
  bf16x8 qf0 = *(const bf16x8*)qp;
  bf16x8 qf1 = *(const bf16x8*)(qp + 32);

  f32x4 oacc[4];
#pragma unroll
  for (int i = 0; i < 4; ++i) oacc[i] = (f32x4){0.f, 0.f, 0.f, 0.f};
  float mrow[4] = {-1e30f, -1e30f, -1e30f, -1e30f};
  float lrow[4] = {0.f, 0.f, 0.f, 0.f};

  for (int j0 = 0; j0 < SEQ; j0 += 64) {
    __syncthreads();  // previous tile's LDS reads done
    // stage K tile + transposed V tile: 64 rows x 8 chunks (16B) = 512 items
#pragma unroll
    for (int c = 0; c < 2; ++c) {
      int id = c * 256 + tid;       // [0,512)
      int jj = id >> 3, dc = id & 7;  // jj in [0,64), dc in [0,8)
      int jr = j0 + jj;
      if (jr > SEQ - 1) jr = SEQ - 1;
      *(bf16x8*)(Ks + jj * 72 + dc * 8) = *(const bf16x8*)(kb + base + (size_t)jr * DHD + dc * 8);
      bf16x8 vv = *(const bf16x8*)(vb + base + (size_t)jr * DHD + dc * 8);
#pragma unroll
      for (int i = 0; i < 8; ++i) Vt[(dc * 8 + i) * 72 + jj] = vv[i];
    }
    __syncthreads();

    // S = Q K^T  (16 rows x 64 cols per wave)
    f32x4 s[4];
#pragma unroll
    for (int sj = 0; sj < 4; ++sj) {
      bf16x8 kf0 = *(const bf16x8*)(Ks + (sj * 16 + r15) * 72 + quad * 8);
      bf16x8 kf1 = *(const bf16x8*)(Ks + (sj * 16 + r15) * 72 + 32 + quad * 8);
      f32x4 z = (f32x4){0.f, 0.f, 0.f, 0.f};
      s[sj] = MFMA_BF16(qf0, kf0, z);
      s[sj] = MFMA_BF16(qf1, kf1, s[sj]);
    }
    // mask j >= SEQ (col = j0 + sj*16 + r15, reg-independent)
#pragma unroll
    for (int sj = 0; sj < 4; ++sj)
      if (j0 + sj * 16 + r15 > SEQ - 1) s[sj] = (f32x4){-1e30f, -1e30f, -1e30f, -1e30f};

    // online softmax per row (rows quad*4+r; reduce across 16 lanes of quad)
#pragma unroll
    for (int r = 0; r < 4; ++r) {
      float mx = fmaxf(fmaxf(s[0][r], s[1][r]), fmaxf(s[2][r], s[3][r]));
      mx = fmaxf(mx, __shfl_xor(mx, 1));
      mx = fmaxf(mx, __shfl_xor(mx, 2));
      mx = fmaxf(mx, __shfl_xor(mx, 4));
      mx = fmaxf(mx, __shfl_xor(mx, 8));
      float mnew = fmaxf(mrow[r], mx);
      float alpha = __expf(mrow[r] - mnew);
      mrow[r] = mnew;
      float rs = 0.f;
#pragma unroll
      for (int sj = 0; sj < 4; ++sj) {
        float e = __expf(s[sj][r] - mnew);
        s[sj][r] = e;
        rs += e;
      }
      rs += __shfl_xor(rs, 1);
      rs += __shfl_xor(rs, 2);
      rs += __shfl_xor(rs, 4);
      rs += __shfl_xor(rs, 8);
      lrow[r] = lrow[r] * alpha + rs;
#pragma unroll
      for (int sd = 0; sd < 4; ++sd) oacc[sd][r] *= alpha;
    }

    // P: C/D layout -> LDS -> A layout (m120-verified transform)
#pragma unroll
    for (int sj = 0; sj < 4; ++sj)
#pragma unroll
      for (int r = 0; r < 4; ++r)
        Pb[wid][(quad * 4 + r) * 72 + sj * 16 + r15] = (bf16)s[sj][r];
    asm volatile("s_waitcnt lgkmcnt(0)" ::: "memory");

    // O += P V
#pragma unroll
    for (int kc = 0; kc < 2; ++kc) {
      bf16x8 pf = *(const bf16x8*)(&Pb[wid][r15 * 72 + kc * 32 + quad * 8]);
#pragma unroll
      for (int sd = 0; sd < 4; ++sd) {
        bf16x8 vf = *(const bf16x8*)(Vt + (sd * 16 + r15) * 72 + kc * 32 + quad * 8);
        oacc[sd] = MFMA_BF16(pf, vf, oacc[sd]);
      }
    }
  }

  // write O/l -> attn_out [b*577+n][h*64+d] bf16
  int b_ = bh / NH, h = bh - b_ * NH;
#pragma unroll
  for (int r = 0; r < 4; ++r) {
    int orow = qt * 64 + wid * 16 + quad * 4 + r;
    if (orow < SEQ) {
      float inv = 1.0f / lrow[r];
      size_t rowoff = ((size_t)(b_ * SEQ + orow)) * CH + h * DHD;
#pragma unroll
      for (int sd = 0; sd < 4; ++sd)
        ob[rowoff + sd * 16 + r15] = (bf16)(oacc[sd][r] * inv);
    }
  }
}

extern "C" void kernel_launch(void* const* d_in, const int* in_sizes, int n_in,
                              void* d_out, int out_size, void* d_ws, size_t ws_size,
                              hipStream_t stream) {
  const float* x      = (const float*)d_in[0];
  const float* qkv_w  = (const float*)d_in[1];
  const float* qkv_b  = (const float*)d_in[2];
  const float* proj_w = (const float*)d_in[3];
  const float* proj_b = (const float*)d_in[4];
  float* out = (float*)d_out;

  char* w = (char*)d_ws;
  // workspace layout (bytes): 118,308,864 total
  bf16* xb   = (bf16*)(w);              // [MPAD,768] bf16 — x, later reused as attn_out
  bf16* wq   = (bf16*)(w + 28508160);   // [2304,768]
  bf16* wp   = (bf16*)(w + 32047104);   // [768,768]
  bf16* qbuf = (bf16*)(w + 33226752);   // [B,H,577,64]
  bf16* kbuf = (bf16*)(w + 61587456);
  bf16* vbuf = (bf16*)(w + 89948160);

  const int nx = MROWS * CH, nxp = MPAD * CH;          // 14,180,352 / 14,254,080
  cvt_bf16<<<(nxp / 4 + 255) / 256, 256, 0, stream>>>(x, xb, nx, nxp);
  cvt_bf16<<<(NQKV * CH / 4 + 255) / 256, 256, 0, stream>>>(qkv_w, wq, NQKV * CH, NQKV * CH);
  cvt_bf16<<<(CH * CH / 4 + 255) / 256, 256, 0, stream>>>(proj_w, wp, CH * CH, CH * CH);

  gemm_bt<0><<<dim3(MPAD / 128, NQKV / 128), 256, 0, stream>>>(
      xb, wq, qkv_b, qbuf, kbuf, vbuf, nullptr);

  attn_kernel<<<dim3(10, BB * NH), 256, 0, stream>>>(qbuf, kbuf, vbuf, xb);

  gemm_bt<1><<<dim3(MPAD / 128, CH / 128), 256, 0, stream>>>(
      xb, wp, proj_b, nullptr, nullptr, nullptr, out);
}

// Round 3
// 448.412 us; speedup vs baseline: 1.0714x; 1.0714x over previous
//
#include <hip/hip_runtime.h>

typedef __bf16 bf16;
typedef __attribute__((ext_vector_type(4))) __bf16 bf16x4;
typedef __attribute__((ext_vector_type(8))) __bf16 bf16x8;
typedef __attribute__((ext_vector_type(4))) float f32x4;

#define MFMA_BF16(A_, B_, C_) __builtin_amdgcn_mfma_f32_16x16x32_bf16(A_, B_, C_, 0, 0, 0)

// Problem dims
#define BB    32
#define SEQ   577
#define CH    768
#define NH    12
#define DHD   64
#define MROWS (BB * SEQ)   // 18464
#define NQKV  2304
#define SEQP  584          // V^T row stride (73*8; staging clamps to start<=576)
// q scale folded with log2(e): softmax computed in base-2 domain
#define QSCALE 0.1803368801111204f

// ---- async global->LDS 16B (wave-uniform LDS base + lane*16, per guide §5) ----
__device__ __forceinline__ void async_ld16(const bf16* g, bf16* l) {
  __builtin_amdgcn_global_load_lds(
      (const __attribute__((address_space(1))) void*)g,
      (__attribute__((address_space(3))) void*)l, 16, 0, 0);
}

// ---- fp32 -> bf16 convert ----
__global__ __launch_bounds__(256) void cvt_bf16(const float* __restrict__ src,
                                                bf16* __restrict__ dst, int n) {
  int idx = (blockIdx.x * 256 + threadIdx.x) * 4;
  if (idx >= n) return;
  float4 v = *(const float4*)(src + idx);
  bf16x4 o = {(bf16)v.x, (bf16)v.y, (bf16)v.z, (bf16)v.w};
  *(bf16x4*)(dst + idx) = o;
}

// ---- 128x128x(K=768) bf16 MFMA GEMM, B given as rows of W [n][k] (x @ W^T) ----
// EPI 0: qkv epilogue: q -> qrm [M,768] (scaled), k -> krm [M,768], v -> vt [B,H,64,SEQP]
// EPI 1: proj epilogue: bias, fp32 out [M,768]
template <int EPI>
__global__ __launch_bounds__(256, 2)
void gemm_bt(const bf16* __restrict__ A, const bf16* __restrict__ W,
             const float* __restrict__ bias,
             bf16* __restrict__ qrm, bf16* __restrict__ krm, bf16* __restrict__ vt,
             float* __restrict__ out) {
  __shared__ bf16 As[128 * 32];
  __shared__ bf16 Bs[128 * 32];
  const int tid = threadIdx.x, lane = tid & 63, wid = tid >> 6;
  const int quad = lane >> 4, r15 = lane & 15;
  const int m0 = blockIdx.x * 128, n0 = blockIdx.y * 128;
  const int waveM = wid & 1, waveN = wid >> 1;

  // staging: 512 16B chunks per tile; XOR chunk swizzle -> fragment ds_read_b128 2-way (free)
  const bf16* aSrc[2];
  const bf16* bSrc[2];
  for (int c = 0; c < 2; ++c) {
    int q = wid * 128 + c * 64 + lane;
    int row = q >> 2;
    int sw = (row ^ (row >> 2)) & 3;
    int kc = (q & 3) ^ sw;
    aSrc[c] = A + (size_t)(m0 + row) * CH + kc * 8;
    bSrc[c] = W + (size_t)(n0 + row) * CH + kc * 8;
  }

  f32x4 acc[4][4];
#pragma unroll
  for (int i = 0; i < 4; ++i)
#pragma unroll
    for (int j = 0; j < 4; ++j) acc[i][j] = (f32x4){0.f, 0.f, 0.f, 0.f};

  for (int k0 = 0; k0 < CH; k0 += 32) {
    __syncthreads();
#pragma unroll
    for (int c = 0; c < 2; ++c) {
      async_ld16(aSrc[c] + k0, As + (wid * 128 + c * 64) * 8);
      async_ld16(bSrc[c] + k0, Bs + (wid * 128 + c * 64) * 8);
    }
    __syncthreads();

    bf16x8 af[4], bfr[4];
#pragma unroll
    for (int s = 0; s < 4; ++s) {
      int rowA = waveM * 64 + s * 16 + r15;
      int ca = quad ^ ((rowA ^ (rowA >> 2)) & 3);
      af[s] = *(const bf16x8*)(As + rowA * 32 + ca * 8);
      int rowB = waveN * 64 + s * 16 + r15;
      int cb = quad ^ ((rowB ^ (rowB >> 2)) & 3);
      bfr[s] = *(const bf16x8*)(Bs + rowB * 32 + cb * 8);
    }
#pragma unroll
    for (int sm = 0; sm < 4; ++sm)
#pragma unroll
      for (int sn = 0; sn < 4; ++sn)
        acc[sm][sn] = MFMA_BF16(af[sm], bfr[sn], acc[sm][sn]);
  }

  // epilogue: C/D layout row=(lane>>4)*4+reg, col=lane&15 (verified m89/m91)
  if (EPI == 0) {
    int t = (n0 >= 1536) ? 2 : (n0 >= 768 ? 1 : 0);  // 128-tiles never straddle 768
#pragma unroll
    for (int sn = 0; sn < 4; ++sn) {
      int gn = n0 + waveN * 64 + sn * 16 + r15;
      float bv = bias[gn];
      int col = gn - t * CH;  // [0,768)
      int h = col >> 6, d = col & 63;
#pragma unroll
      for (int sm = 0; sm < 4; ++sm) {
        int gmBase = m0 + waveM * 64 + sm * 16 + quad * 4;
#pragma unroll
        for (int r = 0; r < 4; ++r) {
          int gm = gmBase + r;
          if (gm < MROWS) {
            float v = acc[sm][sn][r] + bv;
            if (t == 0) {
              qrm[(size_t)gm * CH + col] = (bf16)(v * QSCALE);
            } else if (t == 1) {
              krm[(size_t)gm * CH + col] = (bf16)v;
            } else {
              int b_ = gm / SEQ;
              int n_ = gm - b_ * SEQ;
              vt[((size_t)(b_ * NH + h) * DHD + d) * SEQP + n_] = (bf16)v;
            }
          }
        }
      }
    }
  } else {
#pragma unroll
    for (int sn = 0; sn < 4; ++sn) {
      int gn = n0 + waveN * 64 + sn * 16 + r15;
      float bv = bias[gn];
#pragma unroll
      for (int sm = 0; sm < 4; ++sm) {
        int gmBase = m0 + waveM * 64 + sm * 16 + quad * 4;
#pragma unroll
        for (int r = 0; r < 4; ++r) {
          int gm = gmBase + r;
          if (gm < MROWS) out[(size_t)gm * CH + gn] = acc[sm][sn][r] + bv;
        }
      }
    }
  }
}

// ---- flash attention: block = (64-row q-tile, b*NH+h); 4 waves x 16 q-rows ----
// Q,K row-major [M,768] (head = col slice); V^T [B,H,64,SEQP]. Softmax in exp2 domain.
__global__ __launch_bounds__(256, 4)
void attn_kernel(const bf16* __restrict__ qrm, const bf16* __restrict__ krm,
                 const bf16* __restrict__ vt, bf16* __restrict__ ob) {
  __shared__ bf16 Ks[64 * 72];  // K tile [j][d] pad 72; doubles as P buffer after QK^T
  __shared__ bf16 Vt[64 * 72];  // V^T tile [d][j] pad 72
  const int tid = threadIdx.x, lane = tid & 63, wid = tid >> 6;
  const int quad = lane >> 4, r15 = lane & 15;
  const int qt = blockIdx.x, bh = blockIdx.y;
  const int b_ = bh / NH, h = bh - b_ * NH;
  const bf16* vtb = vt + (size_t)bh * DHD * SEQP;

  // Q fragments resident (A layout: m=lane&15, k=quad*8+j); q pre-scaled by 0.125*log2e
  int qrow = qt * 64 + wid * 16 + r15;
  if (qrow > SEQ - 1) qrow = SEQ - 1;
  const bf16* qp = qrm + (size_t)(b_ * SEQ + qrow) * CH + h * DHD + quad * 8;
  bf16x8 qf0 = *(const bf16x8*)qp;
  bf16x8 qf1 = *(const bf16x8*)(qp + 32);

  f32x4 oacc[4];
#pragma unroll
  for (int i = 0; i < 4; ++i) oacc[i] = (f32x4){0.f, 0.f, 0.f, 0.f};
  float mrow[4] = {-1e30f, -1e30f, -1e30f, -1e30f};
  float lrow[4] = {0.f, 0.f, 0.f, 0.f};

  for (int j0 = 0; j0 < SEQ; j0 += 64) {
    __syncthreads();  // prev tile's Vt/P reads done
    // stage K [64 j x 64 d] and V^T [64 d x 64 j]: 512 x 16B chunks each, b128 writes
#pragma unroll
    for (int c = 0; c < 2; ++c) {
      int id = c * 256 + tid;          // [0,512)
      int row = id >> 3, cc = id & 7;  // row in [0,64), chunk in [0,8)
      int jr = j0 + row;
      if (jr > SEQ - 1) jr = SEQ - 1;
      *(bf16x8*)(Ks + row * 72 + cc * 8) =
          *(const bf16x8*)(krm + (size_t)(b_ * SEQ + jr) * CH + h * DHD + cc * 8);
      int jst = j0 + cc * 8;           // V^T chunk start; clamp keeps reads in-bounds,
      if (jst > SEQ - 1) jst = SEQ - 1;  // mis-staged cols are j>=577 -> P=0
      *(bf16x8*)(Vt + row * 72 + cc * 8) = *(const bf16x8*)(vtb + (size_t)row * SEQP + jst);
    }
    __syncthreads();

    // S = Q K^T (16 q-rows x 64 cols per wave), base-2 domain
    f32x4 s[4];
#pragma unroll
    for (int sj = 0; sj < 4; ++sj) {
      bf16x8 kf0 = *(const bf16x8*)(Ks + (sj * 16 + r15) * 72 + quad * 8);
      bf16x8 kf1 = *(const bf16x8*)(Ks + (sj * 16 + r15) * 72 + 32 + quad * 8);
      f32x4 z = (f32x4){0.f, 0.f, 0.f, 0.f};
      s[sj] = MFMA_BF16(qf0, kf0, z);
      s[sj] = MFMA_BF16(qf1, kf1, s[sj]);
    }
#pragma unroll
    for (int sj = 0; sj < 4; ++sj)
      if (j0 + sj * 16 + r15 > SEQ - 1) s[sj] = (f32x4){-1e30f, -1e30f, -1e30f, -1e30f};

    // online softmax (rows quad*4+r; reduce across the 16 lanes of each quad-group)
#pragma unroll
    for (int r = 0; r < 4; ++r) {
      float mx = fmaxf(fmaxf(s[0][r], s[1][r]), fmaxf(s[2][r], s[3][r]));
      mx = fmaxf(mx, __shfl_xor(mx, 1));
      mx = fmaxf(mx, __shfl_xor(mx, 2));
      mx = fmaxf(mx, __shfl_xor(mx, 4));
      mx = fmaxf(mx, __shfl_xor(mx, 8));
      float mnew = fmaxf(mrow[r], mx);
      float alpha = __builtin_amdgcn_exp2f(mrow[r] - mnew);
      mrow[r] = mnew;
      float rs = 0.f;
#pragma unroll
      for (int sj = 0; sj < 4; ++sj) {
        float e = __builtin_amdgcn_exp2f(s[sj][r] - mnew);
        s[sj][r] = e;
        rs += e;
      }
      rs += __shfl_xor(rs, 1);
      rs += __shfl_xor(rs, 2);
      rs += __shfl_xor(rs, 4);
      rs += __shfl_xor(rs, 8);
      lrow[r] = lrow[r] * alpha + rs;
#pragma unroll
      for (int sd = 0; sd < 4; ++sd) oacc[sd][r] *= alpha;
    }

    __syncthreads();  // all waves done reading Ks before P overwrites it
    // P: C/D layout -> LDS (aliased on Ks) -> A layout
    bf16* Pw = Ks + wid * (16 * 72);
#pragma unroll
    for (int sj = 0; sj < 4; ++sj)
#pragma unroll
      for (int r = 0; r < 4; ++r)
        Pw[(quad * 4 + r) * 72 + sj * 16 + r15] = (bf16)s[sj][r];
    asm volatile("s_waitcnt lgkmcnt(0)" ::: "memory");

    // O += P V
#pragma unroll
    for (int kc = 0; kc < 2; ++kc) {
      bf16x8 pf = *(const bf16x8*)(Pw + r15 * 72 + kc * 32 + quad * 8);
#pragma unroll
      for (int sd = 0; sd < 4; ++sd) {
        bf16x8 vf = *(const bf16x8*)(Vt + (sd * 16 + r15) * 72 + kc * 32 + quad * 8);
        oacc[sd] = MFMA_BF16(pf, vf, oacc[sd]);
      }
    }
  }

  // write O -> attn_out [b*577+n][h*64+d] bf16 row-major
#pragma unroll
  for (int r = 0; r < 4; ++r) {
    int orow = qt * 64 + wid * 16 + quad * 4 + r;
    if (orow < SEQ) {
      float inv = 1.0f / lrow[r];
      size_t rowoff = ((size_t)(b_ * SEQ + orow)) * CH + h * DHD;
#pragma unroll
      for (int sd = 0; sd < 4; ++sd)
        ob[rowoff + sd * 16 + r15] = (bf16)(oacc[sd][r] * inv);
    }
  }
}

extern "C" void kernel_launch(void* const* d_in, const int* in_sizes, int n_in,
                              void* d_out, int out_size, void* d_ws, size_t ws_size,
                              hipStream_t stream) {
  const float* x      = (const float*)d_in[0];
  const float* qkv_w  = (const float*)d_in[1];
  const float* qkv_b  = (const float*)d_in[2];
  const float* proj_w = (const float*)d_in[3];
  const float* proj_b = (const float*)d_in[4];
  float* out = (float*)d_out;

  char* w = (char*)d_ws;
  // workspace layout (bytes), total 117,325,824 (< 118,308,864 known-good):
  bf16* xb  = (bf16*)(w);               // [18464,768] x_bf16, reused as attn_out
  bf16* wqp = (bf16*)(w + 28360704);    // qkv_w bf16; later aliased by proj_w bf16
  bf16* qrm = (bf16*)(w + 31899648);    // [18464,768] scaled Q
  bf16* krm = (bf16*)(w + 60260352);    // [18464,768] K
  bf16* vtb = (bf16*)(w + 88621056);    // [32,12,64,584] V^T
  // GEMM m-tail (rows 18464..18559) reads spill into the wqp region: finite, discarded.

  cvt_bf16<<<(MROWS * CH / 4 + 255) / 256, 256, 0, stream>>>(x, xb, MROWS * CH);
  cvt_bf16<<<(NQKV * CH / 4 + 255) / 256, 256, 0, stream>>>(qkv_w, wqp, NQKV * CH);

  gemm_bt<0><<<dim3(145, NQKV / 128), 256, 0, stream>>>(
      xb, wqp, qkv_b, qrm, krm, vtb, nullptr);

  attn_kernel<<<dim3(10, BB * NH), 256, 0, stream>>>(qrm, krm, vtb, xb);

  // proj weights convert AFTER attention (stream-ordered) so it can alias wqp
  cvt_bf16<<<(CH * CH / 4 + 255) / 256, 256, 0, stream>>>(proj_w, wqp, CH * CH);

  gemm_bt<1><<<dim3(145, CH / 128), 256, 0, stream>>>(
      xb, wqp, proj_b, nullptr, nullptr, nullptr, out);
}